// Round 3
// baseline (9.781 us; speedup 1.0000x reference)
//
#include <hip/hip_runtime.h>

// QuantumAttention, analytic reduction:
//   out[b] = || P_sym^(x)4 · (CZ-ring) · (Rot^(x)8) · (f1 (x) f2) ||^2
// Wave-per-item, 256 amps = 64 lanes x 4 regs.
//   amp bits: b7=r1, b3=r0, b6..b4=lane5..3, b2..b0=lane2..0.
//   wires 0,4 -> in-register; wires 1,2,3,5,6,7 -> shfl_xor 32/16/8/4/2/1.
//   P_sym (7,3) in-register; (6,2),(5,1),(4,0) -> shfl_xor 36/18/9.
// ZERO barriers: each wave computes its own umat copy (intra-wave LDS
// write->read ordered by lgkmcnt, no __syncthreads needed).

__global__ __launch_bounds__(256) void qattn_kernel(const float* __restrict__ x,
                                                    const float* __restrict__ w,
                                                    float* __restrict__ out) {
    const int tid  = threadIdx.x;
    const int lane = tid & 63;
    const int wv   = tid >> 6;
    const int b    = (blockIdx.x << 2) | wv;

    __shared__ float umat[4][8][8];  // per-wave copy: u00r,u00i,u01r,u01i,u10r,u10i,u11r,u11i

    // issue global loads first; latency hides under the sincos chain
    const float* xb = x + b * 32;
    const int lh = lane >> 3, ll = lane & 7;
    const float f1a = xb[lh],      f1b = xb[8 + lh];
    const float f2a = xb[16 + ll], f2b = xb[24 + ll];

    if (lane < 8) {
        const float phi = w[lane * 3 + 0];
        const float th  = w[lane * 3 + 1];
        const float om  = w[lane * 3 + 2];
        float sh, ch;      sincosf(0.5f * th, &sh, &ch);
        float ep_i, ep_r;  sincosf(-0.5f * (phi + om), &ep_i, &ep_r);
        float em_i, em_r;  sincosf( 0.5f * (phi - om), &em_i, &em_r);
        float* u = umat[wv][lane];
        u[0] =  ep_r * ch;   // u00 = ep*c
        u[1] =  ep_i * ch;
        u[2] = -em_r * sh;   // u01 = -em*s
        u[3] = -em_i * sh;
        u[4] =  em_r * sh;   // u10 = conj(em)*s
        u[5] = -em_i * sh;
        u[6] =  ep_r * ch;   // u11 = conj(ep)*c
        u[7] = -ep_i * ch;
    }
    // no barrier: producers and consumers are the same wave

    float ar[4] = { f1a * f2a, f1a * f2b, f1b * f2a, f1b * f2b };
    float ai[4] = { 0.f, 0.f, 0.f, 0.f };

    const float (*um)[8] = umat[wv];

    // --- 6 lane-exchange Rot gates: wires {1,2,3,5,6,7} <-> masks {32,16,8,4,2,1}
    const int gw[6] = {1, 2, 3, 5, 6, 7};
    const int gl[6] = {32, 16, 8, 4, 2, 1};
#pragma unroll
    for (int i = 0; i < 6; ++i) {
        const int g = gw[i], L = gl[i];
        const bool hi = (lane & L) != 0;
        const float uar = hi ? um[g][6] : um[g][0];   // coeff of own amp
        const float uai = hi ? um[g][7] : um[g][1];
        const float ubr = hi ? um[g][4] : um[g][2];   // coeff of partner
        const float ubi = hi ? um[g][5] : um[g][3];
#pragma unroll
        for (int r = 0; r < 4; ++r) {
            const float pr = __shfl_xor(ar[r], L, 64);
            const float pi = __shfl_xor(ai[r], L, 64);
            const float nr = uar * ar[r] - uai * ai[r] + ubr * pr - ubi * pi;
            const float ni = uar * ai[r] + uai * ar[r] + ubr * pi + ubi * pr;
            ar[r] = nr; ai[r] = ni;
        }
    }

    // --- in-register Rot: wire 0 (r-bit1: pairs (0,2),(1,3)), wire 4 (r-bit0: (0,1),(2,3))
    {
        const float u0r=um[0][0],u0i=um[0][1],u1r=um[0][2],u1i=um[0][3];
        const float u2r=um[0][4],u2i=um[0][5],u3r=um[0][6],u3i=um[0][7];
#pragma unroll
        for (int lo = 0; lo < 2; ++lo) {
            const int h2 = lo + 2;
            const float a0r=ar[lo],a0i=ai[lo],a1r=ar[h2],a1i=ai[h2];
            ar[lo] = u0r*a0r-u0i*a0i + u1r*a1r-u1i*a1i;
            ai[lo] = u0r*a0i+u0i*a0r + u1r*a1i+u1i*a1r;
            ar[h2] = u2r*a0r-u2i*a0i + u3r*a1r-u3i*a1i;
            ai[h2] = u2r*a0i+u2i*a0r + u3r*a1i+u3i*a1r;
        }
    }
    {
        const float u0r=um[4][0],u0i=um[4][1],u1r=um[4][2],u1i=um[4][3];
        const float u2r=um[4][4],u2i=um[4][5],u3r=um[4][6],u3i=um[4][7];
#pragma unroll
        for (int p = 0; p < 2; ++p) {
            const int lo = p * 2, h2 = lo + 1;
            const float a0r=ar[lo],a0i=ai[lo],a1r=ar[h2],a1i=ai[h2];
            ar[lo] = u0r*a0r-u0i*a0i + u1r*a1r-u1i*a1i;
            ai[lo] = u0r*a0i+u0i*a0r + u1r*a1i+u1i*a1r;
            ar[h2] = u2r*a0r-u2i*a0i + u3r*a1r-u3i*a1i;
            ai[h2] = u2r*a0i+u2i*a0r + u3r*a1i+u3i*a1r;
        }
    }

    // --- CZ ring sign: parity of cyclic adjacent-bit ANDs of amp index.
    // amp bits: b7=r1, b3=r0, b6..4 = l5..3, b2..0 = l2..0.
    // parity = (l5l4 ^ l4l3 ^ l2l1 ^ l1l0) ^ r1·(l5^l0) ^ r0·(l3^l2)
    {
        const unsigned l0=lane&1, l1=(lane>>1)&1, l2=(lane>>2)&1,
                       l3=(lane>>3)&1, l4=(lane>>4)&1, l5=(lane>>5)&1;
        const unsigned p0 = (l5&l4) ^ (l4&l3) ^ (l2&l1) ^ (l1&l0);
        const unsigned e1 = l5 ^ l0;     // multiplies r-bit1
        const unsigned e0 = l3 ^ l2;     // multiplies r-bit0
#pragma unroll
        for (int r = 0; r < 4; ++r) {
            const unsigned s = p0 ^ ((r >> 1) & e1) ^ (r & e0 & 1);
            if (s) { ar[r] = -ar[r]; ai[r] = -ai[r]; }
        }
    }

    // --- P_sym pair (b7,b3): in-register average of r=1,2
    {
        const float nr = 0.5f * (ar[1] + ar[2]);
        const float ni = 0.5f * (ai[1] + ai[2]);
        ar[1] = ar[2] = nr;  ai[1] = ai[2] = ni;
    }
    // --- P_sym pairs (6,2),(5,1),(4,0): lane xors 36,18,9
    const int pm[3] = {36, 18, 9};
#pragma unroll
    for (int i = 0; i < 3; ++i) {
        const int L = pm[i];
        const bool diff = __popc(lane & L) & 1;   // pair bits differ on this lane
#pragma unroll
        for (int r = 0; r < 4; ++r) {
            const float pr = __shfl_xor(ar[r], L, 64);
            const float pi = __shfl_xor(ai[r], L, 64);
            ar[r] = diff ? 0.5f * (ar[r] + pr) : ar[r];
            ai[r] = diff ? 0.5f * (ai[r] + pi) : ai[r];
        }
    }

    // --- norm^2 + wave reduce
    float val = ar[0]*ar[0] + ai[0]*ai[0];
    val += ar[1]*ar[1] + ai[1]*ai[1];
    val += ar[2]*ar[2] + ai[2]*ai[2];
    val += ar[3]*ar[3] + ai[3]*ai[3];
#pragma unroll
    for (int off = 32; off; off >>= 1) val += __shfl_xor(val, off, 64);
    if (lane == 0) out[b] = val;
}

extern "C" void kernel_launch(void* const* d_in, const int* in_sizes, int n_in,
                              void* d_out, int out_size, void* d_ws, size_t ws_size,
                              hipStream_t stream) {
    const float* x   = (const float*)d_in[0];   // (2048, 32) f32
    const float* w   = (const float*)d_in[1];   // (1, 8, 3) f32
    float*       out = (float*)d_out;           // (2048,) f32
    qattn_kernel<<<out_size / 4, 256, 0, stream>>>(x, w, out);
}